// Round 2
// baseline (107.627 us; speedup 1.0000x reference)
//
#include <hip/hip_runtime.h>
#include <hip/hip_bf16.h>

// Problem constants: B=2, H=1, LQ=LK=512, D=64, HID=128
// rows (B*H*L) = 1024 for q/k/v each.

#define NROWS 1024   // B*H*LQ
#define DD    64
#define HH    128
#define LK_   512
#define QR    4      // query rows per attn block

// ---------------------------------------------------------------------------
// Kernel A: projections.
// grid = 3072 blocks (0..1023 q-rows, 1024..2047 k-rows, 2048..3071 v-rows),
// block = 128 threads.
// Computes xp = x @ Ww + wb  (written to qp/kp/vp),
// and for q rows:  qa' = xp@W1q + b1 , qb' = xp@W1k + b1
// for k rows:      ka  = xp@W1q      , kb  = xp@W1k
// ---------------------------------------------------------------------------
__global__ __launch_bounds__(128)
void proj_kernel(const float* __restrict__ q, const float* __restrict__ k,
                 const float* __restrict__ v,
                 const float* __restrict__ Ww, const float* __restrict__ wb,
                 const float* __restrict__ W1, const float* __restrict__ b1,
                 float* __restrict__ qp, float* __restrict__ kp, float* __restrict__ vp,
                 float* __restrict__ qa, float* __restrict__ qb,
                 float* __restrict__ ka, float* __restrict__ kb)
{
    const int r    = blockIdx.x;
    const int type = r >> 10;      // 0=q,1=k,2=v
    const int idx  = r & 1023;
    const int t    = threadIdx.x;  // 0..127

    const float* src = (type == 0) ? q : (type == 1) ? k : v;

    __shared__ float x[DD];
    __shared__ float xp[DD];

    if (t < DD) x[t] = src[idx * DD + t];
    __syncthreads();

    if (t < DD) {
        float acc = wb[t];
        #pragma unroll
        for (int c = 0; c < DD; ++c) acc = fmaf(x[c], Ww[c * DD + t], acc);
        xp[t] = acc;
        float* dst = (type == 0) ? qp : (type == 1) ? kp : vp;
        dst[idx * DD + t] = acc;
    }
    __syncthreads();

    if (type == 2) return;

    // thread t = output column h of the HID=128 projections
    float accA = 0.f;   // xp @ W1q  (W1 rows 0..63)
    float accB = 0.f;   // xp @ W1k  (W1 rows 64..127)
    #pragma unroll
    for (int d = 0; d < DD; ++d) {
        const float xv = xp[d];
        accA = fmaf(xv, W1[d * HH + t],        accA);
        accB = fmaf(xv, W1[(DD + d) * HH + t], accB);
    }
    if (type == 0) {
        qa[idx * HH + t] = accA + b1[t];
        qb[idx * HH + t] = accB + b1[t];
    } else {
        ka[idx * HH + t] = accA;
        kb[idx * HH + t] = accB;
    }
}

// ---------------------------------------------------------------------------
// Kernel B: fused logits + softmax + PV + output projection.
// grid = 256 blocks (QR=4 query rows each), block = 512 threads (8 waves).
// Thread t owns key column j = t for all 4 rows -> each ka/kb float4 load
// is amortized across 4 rows (L2 traffic /4 vs 1-row-per-block).
// ---------------------------------------------------------------------------
__global__ __launch_bounds__(512)
void attn_kernel(const float* __restrict__ mask,
                 const float* __restrict__ vp,
                 const float* __restrict__ qa, const float* __restrict__ qb,
                 const float* __restrict__ ka, const float* __restrict__ kb,
                 const float* __restrict__ W2, const float* __restrict__ b2,
                 const float* __restrict__ Wd, const float* __restrict__ db,
                 float* __restrict__ out, float* __restrict__ attn)
{
    const int row0 = blockIdx.x * QR;   // first of 4 query rows (same batch: 4|512)
    const int b    = row0 >> 9;
    const int t    = threadIdx.x;       // 0..511 == key column j
    const int wid  = t >> 6;            // wave 0..7
    const int lane = t & 63;

    __shared__ float qa_l[QR][HH];
    __shared__ float qb_l[QR][HH];
    __shared__ float w2_l[HH];
    __shared__ float p[QR][LK_];
    __shared__ float redm[8][QR];
    __shared__ float reds[8][QR];
    __shared__ float opart[8][QR][DD];
    __shared__ float o_l[QR][DD];

    if (t < QR * HH) {
        const int r = t >> 7, h = t & (HH - 1);
        qa_l[r][h] = qa[(row0 + r) * HH + h];
        qb_l[r][h] = qb[(row0 + r) * HH + h];
    }
    if (t < HH) w2_l[t] = W2[t];
    __syncthreads();

    const float b2v = b2[0];
    const int   j    = t;
    const int   jrow = b * LK_ + j;
    const float4* kbr = reinterpret_cast<const float4*>(kb + jrow * HH);
    const float4* kar = reinterpret_cast<const float4*>(ka + jrow * HH);

    // ---- logits: 4 rows x (2 relu-dot terms over HID=128) ----
    float s1[QR] = {0.f, 0.f, 0.f, 0.f};
    float s2[QR] = {0.f, 0.f, 0.f, 0.f};
    #pragma unroll 4
    for (int h4 = 0; h4 < HH / 4; ++h4) {
        const float4 kb4 = kbr[h4];
        const float4 ka4 = kar[h4];
        const int h = h4 * 4;
        const float w0 = w2_l[h + 0], w1 = w2_l[h + 1];
        const float w2v = w2_l[h + 2], w3 = w2_l[h + 3];
        #pragma unroll
        for (int r = 0; r < QR; ++r) {
            s1[r] = fmaf(fmaxf(qa_l[r][h + 0] + kb4.x, 0.f), w0, s1[r]);
            s1[r] = fmaf(fmaxf(qa_l[r][h + 1] + kb4.y, 0.f), w1, s1[r]);
            s1[r] = fmaf(fmaxf(qa_l[r][h + 2] + kb4.z, 0.f), w2v, s1[r]);
            s1[r] = fmaf(fmaxf(qa_l[r][h + 3] + kb4.w, 0.f), w3, s1[r]);
            s2[r] = fmaf(fmaxf(qb_l[r][h + 0] + ka4.x, 0.f), w0, s2[r]);
            s2[r] = fmaf(fmaxf(qb_l[r][h + 1] + ka4.y, 0.f), w1, s2[r]);
            s2[r] = fmaf(fmaxf(qb_l[r][h + 2] + ka4.z, 0.f), w2v, s2[r]);
            s2[r] = fmaf(fmaxf(qb_l[r][h + 3] + ka4.w, 0.f), w3, s2[r]);
        }
    }

    float sv[QR];
    #pragma unroll
    for (int r = 0; r < QR; ++r)
        sv[r] = s1[r] + s2[r] + 2.f * b2v + mask[(row0 + r) * LK_ + j] * (-1e9f);

    // ---- softmax per row over 512 logits (one per thread) ----
    float m[QR];
    #pragma unroll
    for (int r = 0; r < QR; ++r) {
        float mv = sv[r];
        #pragma unroll
        for (int off = 32; off > 0; off >>= 1) mv = fmaxf(mv, __shfl_xor(mv, off));
        m[r] = mv;
        if (lane == 0) redm[wid][r] = mv;
    }
    __syncthreads();
    #pragma unroll
    for (int r = 0; r < QR; ++r) {
        float mv = redm[0][r];
        #pragma unroll
        for (int w = 1; w < 8; ++w) mv = fmaxf(mv, redm[w][r]);
        m[r] = mv;
    }

    float e[QR], sum[QR];
    #pragma unroll
    for (int r = 0; r < QR; ++r) {
        e[r] = expf(sv[r] - m[r]);
        float s = e[r];
        #pragma unroll
        for (int off = 32; off > 0; off >>= 1) s += __shfl_xor(s, off);
        if (lane == 0) reds[wid][r] = s;
    }
    __syncthreads();
    #pragma unroll
    for (int r = 0; r < QR; ++r) {
        float s = reds[0][r];
        #pragma unroll
        for (int w = 1; w < 8; ++w) s += reds[w][r];
        sum[r] = s;
    }

    #pragma unroll
    for (int r = 0; r < QR; ++r) {
        const float pv = e[r] / sum[r];
        p[r][j] = pv;
        attn[(row0 + r) * LK_ + j] = pv;
    }
    __syncthreads();

    // ---- PV: wave wid handles j in [wid*64, wid*64+64), lane = d ----
    float acc[QR] = {0.f, 0.f, 0.f, 0.f};
    {
        const int j0 = wid * 64;
        const float* vpb = vp + (b * LK_ + j0) * DD;
        #pragma unroll 8
        for (int jj = 0; jj < 64; ++jj) {
            const float vv = vpb[jj * DD + lane];
            #pragma unroll
            for (int r = 0; r < QR; ++r)
                acc[r] = fmaf(p[r][j0 + jj], vv, acc[r]);
        }
    }
    #pragma unroll
    for (int r = 0; r < QR; ++r) opart[wid][r][lane] = acc[r];
    __syncthreads();

    // ---- combine 8 wave partials -> o_l ----
    if (t < QR * DD) {
        const int r = t >> 6, d = t & 63;
        float o = opart[0][r][d];
        #pragma unroll
        for (int w = 1; w < 8; ++w) o += opart[w][r][d];
        o_l[r][d] = o;
    }
    __syncthreads();

    // ---- final: out = o @ Wd + db ----
    if (t < QR * DD) {
        const int r = t >> 6, d = t & 63;
        float res = db[d];
        #pragma unroll
        for (int c = 0; c < DD; ++c) res = fmaf(o_l[r][c], Wd[c * DD + d], res);
        out[(row0 + r) * DD + d] = res;
    }
}

extern "C" void kernel_launch(void* const* d_in, const int* in_sizes, int n_in,
                              void* d_out, int out_size, void* d_ws, size_t ws_size,
                              hipStream_t stream)
{
    const float* q    = (const float*)d_in[0];
    const float* k    = (const float*)d_in[1];
    const float* v    = (const float*)d_in[2];
    const float* mask = (const float*)d_in[3];
    const float* Ww   = (const float*)d_in[4];
    const float* wb   = (const float*)d_in[5];
    const float* Wd   = (const float*)d_in[6];
    const float* db   = (const float*)d_in[7];
    const float* W1   = (const float*)d_in[8];
    const float* b1   = (const float*)d_in[9];
    const float* W2   = (const float*)d_in[10];
    const float* b2   = (const float*)d_in[11];

    float* ws = (float*)d_ws;
    float* qp = ws;                 // 1024*64
    float* kp = qp + NROWS * DD;    // 1024*64
    float* vp = kp + NROWS * DD;    // 1024*64
    float* qa = vp + NROWS * DD;    // 1024*128
    float* qb = qa + NROWS * HH;
    float* ka = qb + NROWS * HH;
    float* kb = ka + NROWS * HH;
    // total ws use: (3*65536 + 4*131072)*4 B = ~2.9 MB

    float* out  = (float*)d_out;        // 2*1*512*64
    float* attn = out + NROWS * DD;     // 2*1*512*512

    proj_kernel<<<dim3(3072), dim3(128), 0, stream>>>(
        q, k, v, Ww, wb, W1, b1, qp, kp, vp, qa, qb, ka, kb);

    attn_kernel<<<dim3(NROWS / QR), dim3(512), 0, stream>>>(
        mask, vp, qa, qb, ka, kb, W2, b2, Wd, db, out, attn);
}

// Round 6
// 106.561 us; speedup vs baseline: 1.0100x; 1.0100x over previous
//
#include <hip/hip_runtime.h>
#include <hip/hip_bf16.h>

// Problem constants: B=2, H=1, LQ=LK=512, D=64, HID=128
// rows (B*H*L) = 1024 for q/k/v each.

#define NROWS 1024   // B*H*LQ
#define DD    64
#define HH    128
#define LK_   512
#define QR    4      // query rows per attn block

// ---------------------------------------------------------------------------
// Kernel A: projections.
// grid = 3072 blocks (0..1023 q-rows, 1024..2047 k-rows, 2048..3071 v-rows),
// block = 128 threads.
// Computes xp = x @ Ww + wb  (written to qp/kp/vp),
// and for q rows:  qa' = xp@W1q + b1 , qb' = xp@W1k + b1
// for k rows:      ka  = xp@W1q      , kb  = xp@W1k   (row-major [j][h])
// ---------------------------------------------------------------------------
__global__ __launch_bounds__(128)
void proj_kernel(const float* __restrict__ q, const float* __restrict__ k,
                 const float* __restrict__ v,
                 const float* __restrict__ Ww, const float* __restrict__ wb,
                 const float* __restrict__ W1, const float* __restrict__ b1,
                 float* __restrict__ qp, float* __restrict__ kp, float* __restrict__ vp,
                 float* __restrict__ qa, float* __restrict__ qb,
                 float* __restrict__ ka, float* __restrict__ kb)
{
    const int r    = blockIdx.x;
    const int type = r >> 10;      // 0=q,1=k,2=v
    const int idx  = r & 1023;
    const int t    = threadIdx.x;  // 0..127

    const float* src = (type == 0) ? q : (type == 1) ? k : v;

    __shared__ float x[DD];
    __shared__ float xp[DD];

    if (t < DD) x[t] = src[idx * DD + t];
    __syncthreads();

    if (t < DD) {
        float acc = wb[t];
        #pragma unroll
        for (int c = 0; c < DD; ++c) acc = fmaf(x[c], Ww[c * DD + t], acc);
        xp[t] = acc;
        float* dst = (type == 0) ? qp : (type == 1) ? kp : vp;
        dst[idx * DD + t] = acc;
    }
    __syncthreads();

    if (type == 2) return;

    // thread t = output column h of the HID=128 projections
    float accA = 0.f;   // xp @ W1q  (W1 rows 0..63)
    float accB = 0.f;   // xp @ W1k  (W1 rows 64..127)
    #pragma unroll
    for (int d = 0; d < DD; ++d) {
        const float xv = xp[d];
        accA = fmaf(xv, W1[d * HH + t],        accA);
        accB = fmaf(xv, W1[(DD + d) * HH + t], accB);
    }
    if (type == 0) {
        qa[idx * HH + t] = accA + b1[t];
        qb[idx * HH + t] = accB + b1[t];
    } else {
        ka[idx * HH + t] = accA;
        kb[idx * HH + t] = accB;
    }
}

// ---------------------------------------------------------------------------
// Kernel A2: transpose+interleave k-tables.
// kt[b][h][j] = float2(ka[b,j,h], kb[b,j,h])  -> coalesced float2 reads in attn.
// grid = (8 j-tiles, 2 h-tiles, 2 batches), block = 256.
// 64x64 tiles via LDS with +1 pad (stride 65 -> conflict-free).
// ---------------------------------------------------------------------------
__global__ __launch_bounds__(256)
void trans_kernel(const float* __restrict__ ka, const float* __restrict__ kb,
                  float2* __restrict__ kt)
{
    const int j0 = blockIdx.x * 64;
    const int h0 = blockIdx.y * 64;
    const int b  = blockIdx.z;
    const int tx = threadIdx.x & 63;
    const int ty = threadIdx.x >> 6;   // 0..3

    __shared__ float ta[64][65];
    __shared__ float tb[64][65];

    #pragma unroll
    for (int rr = 0; rr < 16; ++rr) {
        const int jl = ty + rr * 4;
        const int g  = (b * LK_ + j0 + jl) * HH + h0 + tx;
        ta[jl][tx] = ka[g];
        tb[jl][tx] = kb[g];
    }
    __syncthreads();
    #pragma unroll
    for (int rr = 0; rr < 16; ++rr) {
        const int hl = ty + rr * 4;
        kt[(b * HH + h0 + hl) * LK_ + j0 + tx] = make_float2(ta[tx][hl], tb[tx][hl]);
    }
}

// ---------------------------------------------------------------------------
// Kernel B: fused logits + softmax + PV + output projection.
// grid = 256 blocks (QR=4 query rows each), block = 512 threads (8 waves).
// Thread t owns key column j = t. Hot loop:
//   - kt float2 loads: coalesced (lane-consecutive)
//   - qa'/qb'/W2: wave-uniform global reads -> s_load -> SGPR operands
//   - NO LDS in the hot loop.
// ---------------------------------------------------------------------------
__global__ __launch_bounds__(512)
void attn_kernel(const float* __restrict__ mask,
                 const float* __restrict__ vp,
                 const float* __restrict__ qa, const float* __restrict__ qb,
                 const float2* __restrict__ kt,
                 const float* __restrict__ W2, const float* __restrict__ b2,
                 const float* __restrict__ Wd, const float* __restrict__ db,
                 float* __restrict__ out, float* __restrict__ attn)
{
    const int row0 = blockIdx.x * QR;   // first of 4 query rows (4 | 512)
    const int b    = row0 >> 9;
    const int t    = threadIdx.x;       // 0..511 == key column j
    const int wid  = t >> 6;            // wave 0..7
    const int lane = t & 63;
    const int j    = t;

    __shared__ float p[QR][LK_];
    __shared__ float redm[8][QR];
    __shared__ float reds[8][QR];
    __shared__ float opart[8][QR][DD];
    __shared__ float o_l[QR][DD];

    const float2* ktb = kt + b * HH * LK_;
    const float*  qaR = qa + row0 * HH;   // uniform base
    const float*  qbR = qb + row0 * HH;

    // ---- logits: 4 rows x (2 relu-dot terms over HID=128) ----
    float s1[QR] = {0.f, 0.f, 0.f, 0.f};
    float s2[QR] = {0.f, 0.f, 0.f, 0.f};
    #pragma unroll 8
    for (int h = 0; h < HH; ++h) {
        const float2 kv = ktb[h * LK_ + j];   // .x = ka, .y = kb
        const float  w  = W2[h];              // uniform -> SGPR
        #pragma unroll
        for (int r = 0; r < QR; ++r) {
            s1[r] = fmaf(fmaxf(qaR[r * HH + h] + kv.y, 0.f), w, s1[r]);
            s2[r] = fmaf(fmaxf(qbR[r * HH + h] + kv.x, 0.f), w, s2[r]);
        }
    }

    const float b2v = b2[0];
    float sv[QR];
    #pragma unroll
    for (int r = 0; r < QR; ++r)
        sv[r] = s1[r] + s2[r] + 2.f * b2v + mask[(row0 + r) * LK_ + j] * (-1e9f);

    // ---- softmax per row over 512 logits (one per thread) ----
    float m[QR];
    #pragma unroll
    for (int r = 0; r < QR; ++r) {
        float mv = sv[r];
        #pragma unroll
        for (int off = 32; off > 0; off >>= 1) mv = fmaxf(mv, __shfl_xor(mv, off));
        m[r] = mv;
        if (lane == 0) redm[wid][r] = mv;
    }
    __syncthreads();
    #pragma unroll
    for (int r = 0; r < QR; ++r) {
        float mv = redm[0][r];
        #pragma unroll
        for (int w = 1; w < 8; ++w) mv = fmaxf(mv, redm[w][r]);
        m[r] = mv;
    }

    float e[QR], sum[QR];
    #pragma unroll
    for (int r = 0; r < QR; ++r) {
        e[r] = expf(sv[r] - m[r]);
        float s = e[r];
        #pragma unroll
        for (int off = 32; off > 0; off >>= 1) s += __shfl_xor(s, off);
        if (lane == 0) reds[wid][r] = s;
    }
    __syncthreads();
    #pragma unroll
    for (int r = 0; r < QR; ++r) {
        float s = reds[0][r];
        #pragma unroll
        for (int w = 1; w < 8; ++w) s += reds[w][r];
        sum[r] = s;
    }

    #pragma unroll
    for (int r = 0; r < QR; ++r) {
        const float pv = e[r] / sum[r];
        p[r][j] = pv;
        attn[(row0 + r) * LK_ + j] = pv;
    }
    __syncthreads();

    // ---- PV: wave wid handles j in [wid*64, wid*64+64), lane = d ----
    float acc[QR] = {0.f, 0.f, 0.f, 0.f};
    {
        const int j0 = wid * 64;
        const float* vpb = vp + (b * LK_ + j0) * DD;
        #pragma unroll 8
        for (int jj = 0; jj < 64; ++jj) {
            const float vv = vpb[jj * DD + lane];
            #pragma unroll
            for (int r = 0; r < QR; ++r)
                acc[r] = fmaf(p[r][j0 + jj], vv, acc[r]);
        }
    }
    #pragma unroll
    for (int r = 0; r < QR; ++r) opart[wid][r][lane] = acc[r];
    __syncthreads();

    // ---- combine 8 wave partials -> o_l ----
    if (t < QR * DD) {
        const int r = t >> 6, d = t & 63;
        float o = opart[0][r][d];
        #pragma unroll
        for (int w = 1; w < 8; ++w) o += opart[w][r][d];
        o_l[r][d] = o;
    }
    __syncthreads();

    // ---- final: out = o @ Wd + db ----
    if (t < QR * DD) {
        const int r = t >> 6, d = t & 63;
        float res = db[d];
        #pragma unroll
        for (int c = 0; c < DD; ++c) res = fmaf(o_l[r][c], Wd[c * DD + d], res);
        out[(row0 + r) * DD + d] = res;
    }
}

extern "C" void kernel_launch(void* const* d_in, const int* in_sizes, int n_in,
                              void* d_out, int out_size, void* d_ws, size_t ws_size,
                              hipStream_t stream)
{
    const float* q    = (const float*)d_in[0];
    const float* k    = (const float*)d_in[1];
    const float* v    = (const float*)d_in[2];
    const float* mask = (const float*)d_in[3];
    const float* Ww   = (const float*)d_in[4];
    const float* wb   = (const float*)d_in[5];
    const float* Wd   = (const float*)d_in[6];
    const float* db   = (const float*)d_in[7];
    const float* W1   = (const float*)d_in[8];
    const float* b1   = (const float*)d_in[9];
    const float* W2   = (const float*)d_in[10];
    const float* b2   = (const float*)d_in[11];

    float* ws = (float*)d_ws;
    float* qp = ws;                 // 1024*64
    float* kp = qp + NROWS * DD;
    float* vp = kp + NROWS * DD;
    float* qa = vp + NROWS * DD;    // 1024*128
    float* qb = qa + NROWS * HH;
    float* ka = qb + NROWS * HH;
    float* kb = ka + NROWS * HH;
    float2* kt = (float2*)(kb + NROWS * HH);  // 2*128*512 float2 = 2 MB
    // total ws use ≈ 4.9 MB

    float* out  = (float*)d_out;        // 2*1*512*64
    float* attn = out + NROWS * DD;     // 2*1*512*512

    proj_kernel<<<dim3(3072), dim3(128), 0, stream>>>(
        q, k, v, Ww, wb, W1, b1, qp, kp, vp, qa, qb, ka, kb);

    trans_kernel<<<dim3(8, 2, 2), dim3(256), 0, stream>>>(ka, kb, kt);

    attn_kernel<<<dim3(NROWS / QR), dim3(512), 0, stream>>>(
        mask, vp, qa, qb, kt, W2, b2, Wd, db, out, attn);
}